// Round 1
// baseline (1407.035 us; speedup 1.0000x reference)
//
#include <hip/hip_runtime.h>

#define NB 16
#define CX 256
#define TX 2048
#define TY 2048
#define SCALE 0.0625f  // 1/sqrt(256)

// ---------------------------------------------------------------------------
// Kernel 1: S[n][t][y] = SCALE * sum_c K[n][c][t] * Q[n][c][y]
// Both operands are k-major (c outer, t/y contiguous) -> coalesced tile loads,
// LDS tiles already in [k][m] layout. 128x128x16 tile, 256 thr, 8x8 microtile
// in split 4+4 layout (b-frag reads 2-way bank aliased = free per m136).
// ---------------------------------------------------------------------------
__global__ __launch_bounds__(256) void k_scores(const float* __restrict__ K,
                                                const float* __restrict__ Q,
                                                float* __restrict__ S) {
    __shared__ float Ks[16][128];
    __shared__ float Qs[16][128];
    const int tid = threadIdx.x;
    const int n  = blockIdx.z;
    const int m0 = blockIdx.y * 128;   // t-tile
    const int y0 = blockIdx.x * 128;   // y-tile

    const float* Kp = K + (size_t)n * CX * TX + m0;
    const float* Qp = Q + (size_t)n * CX * TY + y0;

    const int lr = tid >> 5;          // 0..7
    const int lc = (tid & 31) << 2;   // 0,4,...,124
    const int ty = tid >> 4;          // 0..15 (m dir)
    const int tx = tid & 15;          // 0..15 (y dir)

    float acc[8][8];
#pragma unroll
    for (int i = 0; i < 8; ++i)
#pragma unroll
        for (int j = 0; j < 8; ++j) acc[i][j] = 0.f;

    for (int k0 = 0; k0 < CX; k0 += 16) {
        *(float4*)&Ks[lr][lc]     = *(const float4*)(Kp + (size_t)(k0 + lr) * TX + lc);
        *(float4*)&Ks[lr + 8][lc] = *(const float4*)(Kp + (size_t)(k0 + lr + 8) * TX + lc);
        *(float4*)&Qs[lr][lc]     = *(const float4*)(Qp + (size_t)(k0 + lr) * TY + lc);
        *(float4*)&Qs[lr + 8][lc] = *(const float4*)(Qp + (size_t)(k0 + lr + 8) * TY + lc);
        __syncthreads();
#pragma unroll
        for (int k = 0; k < 16; ++k) {
            float4 a0 = *(float4*)&Ks[k][ty * 4];
            float4 a1 = *(float4*)&Ks[k][64 + ty * 4];
            float4 b0 = *(float4*)&Qs[k][tx * 4];
            float4 b1 = *(float4*)&Qs[k][64 + tx * 4];
            float a[8] = {a0.x, a0.y, a0.z, a0.w, a1.x, a1.y, a1.z, a1.w};
            float b[8] = {b0.x, b0.y, b0.z, b0.w, b1.x, b1.y, b1.z, b1.w};
#pragma unroll
            for (int i = 0; i < 8; ++i)
#pragma unroll
                for (int j = 0; j < 8; ++j)
                    acc[i][j] = fmaf(a[i], b[j], acc[i][j]);
        }
        __syncthreads();
    }

    float* Sp = S + (size_t)n * TX * TY + (size_t)m0 * TY + y0;
#pragma unroll
    for (int mi = 0; mi < 8; ++mi) {
        int row = (mi < 4) ? (ty * 4 + mi) : (64 + ty * 4 + mi - 4);
        float4 o0 = make_float4(acc[mi][0] * SCALE, acc[mi][1] * SCALE,
                                acc[mi][2] * SCALE, acc[mi][3] * SCALE);
        float4 o1 = make_float4(acc[mi][4] * SCALE, acc[mi][5] * SCALE,
                                acc[mi][6] * SCALE, acc[mi][7] * SCALE);
        *(float4*)(Sp + (size_t)row * TY + tx * 4)      = o0;
        *(float4*)(Sp + (size_t)row * TY + 64 + tx * 4) = o1;
    }
}

// ---------------------------------------------------------------------------
// Kernel 2: in-place softmax over t (stride-TY) per (n,y) column.
// Block: 64 y-columns x 4 t-slices (512 t each). Online max/sum per slice,
// LDS merge of 4 partials, then normalize+write pass.
// ---------------------------------------------------------------------------
__global__ __launch_bounds__(256) void k_softmax(float* __restrict__ S) {
    __shared__ float ms[256], ls[256];
    __shared__ float mf[64], li[64];
    const int tid = threadIdx.x;
    const int n = blockIdx.y;
    const int yl = tid & 63;
    const int y = blockIdx.x * 64 + yl;
    const int slice = tid >> 6;
    float* col = S + (size_t)n * TX * TY + y;
    const int t0 = slice * 512;

    float m = -1e30f, l = 0.f;
    for (int t = t0; t < t0 + 512; ++t) {
        float s = col[(size_t)t * TY];
        if (s <= m) {
            l += __expf(s - m);
        } else {
            l = l * __expf(m - s) + 1.0f;
            m = s;
        }
    }
    ms[tid] = m;
    ls[tid] = l;
    __syncthreads();
    if (tid < 64) {
        float M = ms[tid];
        float L = ls[tid];
#pragma unroll
        for (int s2 = 1; s2 < 4; ++s2) {
            float m2 = ms[s2 * 64 + tid], l2 = ls[s2 * 64 + tid];
            float nm = fmaxf(M, m2);
            L = L * __expf(M - nm) + l2 * __expf(m2 - nm);
            M = nm;
        }
        mf[tid] = M;
        li[tid] = 1.0f / L;
    }
    __syncthreads();
    const float M = mf[yl];
    const float inv = li[yl];
    for (int t = t0; t < t0 + 512; ++t) {
        float s = col[(size_t)t * TY];
        col[(size_t)t * TY] = __expf(s - M) * inv;
    }
}

// ---------------------------------------------------------------------------
// Kernel 3: R[n][c][y] = sum_t V[n][c][t] * A[n][t][y]
// V is m-major (t contiguous) -> transpose-on-store into Vs[k][m] with pad
// stride 132 (2-way bank aliasing on writes = free). A is k-major.
// ---------------------------------------------------------------------------
__global__ __launch_bounds__(256) void k_pv(const float* __restrict__ V,
                                            const float* __restrict__ A,
                                            float* __restrict__ R) {
    __shared__ float Vs[16][132];
    __shared__ float As[16][128];
    const int tid = threadIdx.x;
    const int n  = blockIdx.z;
    const int c0 = blockIdx.y * 128;
    const int y0 = blockIdx.x * 128;

    const float* Vp = V + (size_t)n * CX * TX + (size_t)c0 * TX;
    const float* Ap = A + (size_t)n * TX * TY + y0;

    const int vr = tid >> 2;          // 0..63 (c row)
    const int vq = (tid & 3) << 2;    // 0,4,8,12 (k col)
    const int lr = tid >> 5;
    const int lc = (tid & 31) << 2;
    const int ty = tid >> 4;
    const int tx = tid & 15;

    float acc[8][8];
#pragma unroll
    for (int i = 0; i < 8; ++i)
#pragma unroll
        for (int j = 0; j < 8; ++j) acc[i][j] = 0.f;

    for (int k0 = 0; k0 < TX; k0 += 16) {
        float4 v0 = *(const float4*)(Vp + (size_t)vr * TX + k0 + vq);
        float4 v1 = *(const float4*)(Vp + (size_t)(vr + 64) * TX + k0 + vq);
        *(float4*)&As[lr][lc]     = *(const float4*)(Ap + (size_t)(k0 + lr) * TY + lc);
        *(float4*)&As[lr + 8][lc] = *(const float4*)(Ap + (size_t)(k0 + lr + 8) * TY + lc);
        Vs[vq + 0][vr] = v0.x;
        Vs[vq + 1][vr] = v0.y;
        Vs[vq + 2][vr] = v0.z;
        Vs[vq + 3][vr] = v0.w;
        Vs[vq + 0][vr + 64] = v1.x;
        Vs[vq + 1][vr + 64] = v1.y;
        Vs[vq + 2][vr + 64] = v1.z;
        Vs[vq + 3][vr + 64] = v1.w;
        __syncthreads();
#pragma unroll
        for (int k = 0; k < 16; ++k) {
            float4 a0 = *(float4*)&Vs[k][ty * 4];
            float4 a1 = *(float4*)&Vs[k][64 + ty * 4];
            float4 b0 = *(float4*)&As[k][tx * 4];
            float4 b1 = *(float4*)&As[k][64 + tx * 4];
            float a[8] = {a0.x, a0.y, a0.z, a0.w, a1.x, a1.y, a1.z, a1.w};
            float b[8] = {b0.x, b0.y, b0.z, b0.w, b1.x, b1.y, b1.z, b1.w};
#pragma unroll
            for (int i = 0; i < 8; ++i)
#pragma unroll
                for (int j = 0; j < 8; ++j)
                    acc[i][j] = fmaf(a[i], b[j], acc[i][j]);
        }
        __syncthreads();
    }

    float* Rp = R + (size_t)n * CX * TY + (size_t)c0 * TY + y0;
#pragma unroll
    for (int mi = 0; mi < 8; ++mi) {
        int row = (mi < 4) ? (ty * 4 + mi) : (64 + ty * 4 + mi - 4);
        float4 o0 = make_float4(acc[mi][0], acc[mi][1], acc[mi][2], acc[mi][3]);
        float4 o1 = make_float4(acc[mi][4], acc[mi][5], acc[mi][6], acc[mi][7]);
        *(float4*)(Rp + (size_t)row * TY + tx * 4)      = o0;
        *(float4*)(Rp + (size_t)row * TY + 64 + tx * 4) = o1;
    }
}

extern "C" void kernel_launch(void* const* d_in, const int* in_sizes, int n_in,
                              void* d_out, int out_size, void* d_ws, size_t ws_size,
                              hipStream_t stream) {
    const float* K = (const float*)d_in[0];
    const float* V = (const float*)d_in[1];
    const float* Q = (const float*)d_in[2];
    float* R = (float*)d_out;
    float* A = (float*)d_out + (size_t)NB * CX * TY;  // A region of d_out

    dim3 blk(256);
    // 1) raw scaled scores into the A output region
    k_scores<<<dim3(TY / 128, TX / 128, NB), blk, 0, stream>>>(K, Q, A);
    // 2) in-place column softmax over t
    k_softmax<<<dim3(TY / 64, NB), blk, 0, stream>>>(A);
    // 3) R = V * A
    k_pv<<<dim3(TY / 128, CX / 128, NB), blk, 0, stream>>>(V, A, R);
}

// Round 2
// 803.682 us; speedup vs baseline: 1.7507x; 1.7507x over previous
//
#include <hip/hip_runtime.h>

#define NB 16
#define CX 256
#define TX 2048
#define TY 2048
#define SCALE 0.0625f  // 1/sqrt(256), exact power of two

typedef __attribute__((ext_vector_type(8))) short short8;
typedef __attribute__((ext_vector_type(4))) short short4v;
typedef __attribute__((ext_vector_type(4))) float floatx4;

// fp32 -> bf16 (RNE). On gfx950 the __bf16 cast lowers to v_cvt_pk_bf16_f32.
static __device__ __forceinline__ short f2bf(float x) {
#if defined(__gfx950__)
    __bf16 b = (__bf16)x;
    return __builtin_bit_cast(short, b);
#else
    union { float f; unsigned u; } v; v.f = x;
    unsigned r = v.u + 0x7fff + ((v.u >> 16) & 1);
    return (short)(r >> 16);
#endif
}

// ---------------------------------------------------------------------------
// Kernel 1: S[n][t][y] = sum_c (K[n][c][t]*SCALE)_bf16 * Q[n][c][y]_bf16
// 128x128x32 tile, 256 thr / 4 waves, each wave 4x4 grid of 16x16x32 MFMA.
// Both operands k-major in global -> transpose-on-stage: strided-c dword
// loads (coalesced across lanes in t/y), pack 4 bf16, ds_write_b64.
// LDS row stride 40 bf16 = 80 B: b128 frag reads land 2-way aliased (free).
// ---------------------------------------------------------------------------
__global__ __launch_bounds__(256) void k_scores(const float* __restrict__ K,
                                                const float* __restrict__ Q,
                                                float* __restrict__ S) {
    __shared__ short Ash[128][40];
    __shared__ short Bsh[128][40];
    const int tid = threadIdx.x;
    const int n  = blockIdx.z;
    const int m0 = blockIdx.y * 128;   // t
    const int y0 = blockIdx.x * 128;   // y

    const float* Ka = K + (size_t)n * CX * TX + m0;
    const float* Qa = Q + (size_t)n * CX * TY + y0;

    const int sm = tid & 127;          // staging row (m or y)
    const int kh = tid >> 7;           // k half (0/1)

    const int lane = tid & 63;
    const int w    = tid >> 6;
    const int wm   = (w >> 1) * 64;
    const int wn   = (w & 1) * 64;
    const int fr   = lane & 15;
    const int fq   = lane >> 4;

    floatx4 acc[4][4];
#pragma unroll
    for (int i = 0; i < 4; ++i)
#pragma unroll
        for (int j = 0; j < 4; ++j) acc[i][j] = (floatx4)0.f;

    for (int k0 = 0; k0 < CX; k0 += 32) {
#pragma unroll
        for (int g = 0; g < 4; ++g) {
            const int c = k0 + kh * 16 + g * 4;
            float a0 = Ka[(size_t)(c + 0) * TX + sm];
            float a1 = Ka[(size_t)(c + 1) * TX + sm];
            float a2 = Ka[(size_t)(c + 2) * TX + sm];
            float a3 = Ka[(size_t)(c + 3) * TX + sm];
            short4v av = {f2bf(a0 * SCALE), f2bf(a1 * SCALE),
                          f2bf(a2 * SCALE), f2bf(a3 * SCALE)};
            *(short4v*)&Ash[sm][kh * 16 + g * 4] = av;
            float b0 = Qa[(size_t)(c + 0) * TY + sm];
            float b1 = Qa[(size_t)(c + 1) * TY + sm];
            float b2 = Qa[(size_t)(c + 2) * TY + sm];
            float b3 = Qa[(size_t)(c + 3) * TY + sm];
            short4v bv = {f2bf(b0), f2bf(b1), f2bf(b2), f2bf(b3)};
            *(short4v*)&Bsh[sm][kh * 16 + g * 4] = bv;
        }
        __syncthreads();
        short8 af[4], bf[4];
#pragma unroll
        for (int mt = 0; mt < 4; ++mt)
            af[mt] = *(short8*)&Ash[wm + mt * 16 + fr][fq * 8];
#pragma unroll
        for (int nt = 0; nt < 4; ++nt)
            bf[nt] = *(short8*)&Bsh[wn + nt * 16 + fr][fq * 8];
#pragma unroll
        for (int mt = 0; mt < 4; ++mt)
#pragma unroll
            for (int nt = 0; nt < 4; ++nt)
                acc[mt][nt] = __builtin_amdgcn_mfma_f32_16x16x32_bf16(
                    af[mt], bf[nt], acc[mt][nt], 0, 0, 0);
        __syncthreads();
    }

    float* Sp = S + (size_t)n * TX * TY;
#pragma unroll
    for (int mt = 0; mt < 4; ++mt) {
#pragma unroll
        for (int reg = 0; reg < 4; ++reg) {
            const int row = m0 + wm + mt * 16 + fq * 4 + reg;
#pragma unroll
            for (int nt = 0; nt < 4; ++nt) {
                const int col = y0 + wn + nt * 16 + fr;
                Sp[(size_t)row * TY + col] = acc[mt][nt][reg];
            }
        }
    }
}

// ---------------------------------------------------------------------------
// Kernel 2: in-place softmax over t per (n,y) column. 64 y per block as
// 16 quads of float4; 16 t-slices of 128. Branchless online max/sum with
// 4-wide ILP, float4 loads/stores.
// ---------------------------------------------------------------------------
__global__ __launch_bounds__(256) void k_softmax(float* __restrict__ S) {
    __shared__ floatx4 ms[256], ls[256];
    __shared__ floatx4 Mf[16], Li[16];
    const int tid = threadIdx.x;
    const int n  = blockIdx.y;
    const int yq = tid & 15;
    const int sl = tid >> 4;
    const int y0 = blockIdx.x * 64;
    float* base = S + (size_t)n * TX * TY + y0 + yq * 4;
    const int t0 = sl * 128;

    floatx4 m4 = {-1e30f, -1e30f, -1e30f, -1e30f};
    floatx4 l4 = {0.f, 0.f, 0.f, 0.f};
    for (int t = t0; t < t0 + 128; ++t) {
        floatx4 v = *(floatx4*)(base + (size_t)t * TY);
#pragma unroll
        for (int c = 0; c < 4; ++c) {
            float nm = fmaxf(m4[c], v[c]);
            l4[c] = l4[c] * __expf(m4[c] - nm) + __expf(v[c] - nm);
            m4[c] = nm;
        }
    }
    ms[tid] = m4;
    ls[tid] = l4;
    __syncthreads();
    if (tid < 16) {
        floatx4 M = ms[tid];      // sl = 0 entry for yq = tid
        floatx4 L = ls[tid];
        for (int s2 = 1; s2 < 16; ++s2) {
            floatx4 m2 = ms[s2 * 16 + tid];
            floatx4 l2 = ls[s2 * 16 + tid];
#pragma unroll
            for (int c = 0; c < 4; ++c) {
                float nm = fmaxf(M[c], m2[c]);
                L[c] = L[c] * __expf(M[c] - nm) + l2[c] * __expf(m2[c] - nm);
                M[c] = nm;
            }
        }
        floatx4 I;
#pragma unroll
        for (int c = 0; c < 4; ++c) I[c] = 1.0f / L[c];
        Mf[tid] = M;
        Li[tid] = I;
    }
    __syncthreads();
    const floatx4 M4 = Mf[yq];
    const floatx4 I4 = Li[yq];
    for (int t = t0; t < t0 + 128; ++t) {
        floatx4 v = *(floatx4*)(base + (size_t)t * TY);
        floatx4 r;
#pragma unroll
        for (int c = 0; c < 4; ++c) r[c] = __expf(v[c] - M4[c]) * I4[c];
        *(floatx4*)(base + (size_t)t * TY) = r;
    }
}

// ---------------------------------------------------------------------------
// Kernel 3: R[n][c][y] = sum_t V[n][c][t]_bf16 * A[n][t][y]_bf16
// V is k-contiguous (direct bf16 pack + straight LDS write); A needs the
// same transpose-staging as kernel 1.
// ---------------------------------------------------------------------------
__global__ __launch_bounds__(256) void k_pv(const float* __restrict__ V,
                                            const float* __restrict__ A,
                                            float* __restrict__ R) {
    __shared__ short Vsh[128][40];
    __shared__ short Bsh[128][40];
    const int tid = threadIdx.x;
    const int n  = blockIdx.z;
    const int c0 = blockIdx.y * 128;
    const int y0 = blockIdx.x * 128;

    const float* Vp = V + (size_t)n * CX * TX;
    const float* Ap = A + (size_t)n * TX * TY + y0;

    // V staging map: 8 t-chunks x 32 c-rows
    const int tt = tid & 7;            // t chunk (x4)
    const int tc = tid >> 3;           // c row (0..31), +32 per cc
    // A staging map (transpose)
    const int sy = tid & 127;
    const int kh = tid >> 7;

    const int lane = tid & 63;
    const int w    = tid >> 6;
    const int wm   = (w >> 1) * 64;
    const int wn   = (w & 1) * 64;
    const int fr   = lane & 15;
    const int fq   = lane >> 4;

    floatx4 acc[4][4];
#pragma unroll
    for (int i = 0; i < 4; ++i)
#pragma unroll
        for (int j = 0; j < 4; ++j) acc[i][j] = (floatx4)0.f;

    for (int k0 = 0; k0 < TX; k0 += 32) {
#pragma unroll
        for (int cc = 0; cc < 4; ++cc) {
            const int c = c0 + cc * 32 + tc;
            float4 v = *(const float4*)(Vp + (size_t)c * TX + k0 + tt * 4);
            short4v sv = {f2bf(v.x), f2bf(v.y), f2bf(v.z), f2bf(v.w)};
            *(short4v*)&Vsh[cc * 32 + tc][tt * 4] = sv;
        }
#pragma unroll
        for (int g = 0; g < 4; ++g) {
            const int t = k0 + kh * 16 + g * 4;
            float b0 = Ap[(size_t)(t + 0) * TY + sy];
            float b1 = Ap[(size_t)(t + 1) * TY + sy];
            float b2 = Ap[(size_t)(t + 2) * TY + sy];
            float b3 = Ap[(size_t)(t + 3) * TY + sy];
            short4v bv = {f2bf(b0), f2bf(b1), f2bf(b2), f2bf(b3)};
            *(short4v*)&Bsh[sy][kh * 16 + g * 4] = bv;
        }
        __syncthreads();
        short8 af[4], bf[4];
#pragma unroll
        for (int mt = 0; mt < 4; ++mt)
            af[mt] = *(short8*)&Vsh[wm + mt * 16 + fr][fq * 8];
#pragma unroll
        for (int nt = 0; nt < 4; ++nt)
            bf[nt] = *(short8*)&Bsh[wn + nt * 16 + fr][fq * 8];
#pragma unroll
        for (int mt = 0; mt < 4; ++mt)
#pragma unroll
            for (int nt = 0; nt < 4; ++nt)
                acc[mt][nt] = __builtin_amdgcn_mfma_f32_16x16x32_bf16(
                    af[mt], bf[nt], acc[mt][nt], 0, 0, 0);
        __syncthreads();
    }

    float* Rp = R + (size_t)n * CX * TY;
#pragma unroll
    for (int mt = 0; mt < 4; ++mt) {
#pragma unroll
        for (int reg = 0; reg < 4; ++reg) {
            const int row = c0 + wm + mt * 16 + fq * 4 + reg;
#pragma unroll
            for (int nt = 0; nt < 4; ++nt) {
                const int col = y0 + wn + nt * 16 + fr;
                Rp[(size_t)row * TY + col] = acc[mt][nt][reg];
            }
        }
    }
}

extern "C" void kernel_launch(void* const* d_in, const int* in_sizes, int n_in,
                              void* d_out, int out_size, void* d_ws, size_t ws_size,
                              hipStream_t stream) {
    const float* K = (const float*)d_in[0];
    const float* V = (const float*)d_in[1];
    const float* Q = (const float*)d_in[2];
    float* R = (float*)d_out;
    float* A = (float*)d_out + (size_t)NB * CX * TY;

    dim3 blk(256);
    k_scores<<<dim3(TY / 128, TX / 128, NB), blk, 0, stream>>>(K, Q, A);
    k_softmax<<<dim3(TY / 64, NB), blk, 0, stream>>>(A);
    k_pv<<<dim3(TY / 128, CX / 128, NB), blk, 0, stream>>>(V, A, R);
}